// Round 11
// baseline (326.640 us; speedup 1.0000x reference)
//
#include <hip/hip_runtime.h>
#include <hip/hip_fp16.h>
#include <hip/hip_cooperative_groups.h>

namespace cg = cooperative_groups;

typedef _Float16 f16x4  __attribute__((ext_vector_type(4)));
typedef float    f32x16 __attribute__((ext_vector_type(16)));

constexpr int Nn = 8192;
constexpr int Dd = 256;

constexpr int BM  = 256;        // I-rows per GEMM tile
constexpr int KC  = 1024;       // K range per GEMM tile
constexpr int SK  = 64;         // staged K subchunk
constexpr int NSC = KC / SK;    // 16 subchunks
constexpr int NB  = 4;          // LDS buffers, stage 3 ahead
constexpr int ABYTES = BM * SK; // 16 KB per A buffer (fp8)
constexpr int YBYTES = Dd * SK; // 16 KB per Yt buffer (fp8)

#define AS1 __attribute__((address_space(1)))
#define AS3 __attribute__((address_space(3)))
#define WAITV(N) asm volatile("s_waitcnt vmcnt(" #N ")" ::: "memory")

// ===========================================================================
// MEGA: one cooperative kernel, 256 blocks x 1024 thr (1 block/CU).
//  P1 (pre-sync):  rows b*32..b*32+31: rowsum(A) -> disL/rdL (LDS only!) and
//                  Af8 = e4m3(A) write-out.  Block 0 zeroes s/T/cnt.
//  P2 (pre-sync):  same rows: Zn, Yr(f16), tile = fp8(64*Y) transposed,
//                  sacc[k] += Zn (block-local colsum).
//  -- one grid.sync() --
//  P3: GEMM tile (ib = b&31, jb = b>>5), identical to validated round-10
//      k_main (fp8 MFMA, 4-deep DMA queue, counted vmcnt).
//  P4: last-finished block (atomic ticket) computes out[0..1].
// ===========================================================================
__global__ __launch_bounds__(1024, 4) void k_mega(
    const float* __restrict__ A, const float* __restrict__ Z,
    unsigned char* __restrict__ Af8, unsigned char* __restrict__ Ytf8,
    _Float16* __restrict__ Yr, float* __restrict__ s,
    float* __restrict__ T, unsigned int* __restrict__ cnt,
    float* __restrict__ out)
{
    __shared__ long SM[16384];   // 128 KB, phase-aliased
    __shared__ int  islast;
    char* smem = (char*)SM;
    unsigned char (*tile)[40] = (unsigned char(*)[40])smem;   // 256 x 40 B
    float* sacc = (float*)(smem + 10496);   // 1 KB
    float* disL = (float*)(smem + 11776);   // 128 B
    float* rdL  = (float*)(smem + 11904);   // 128 B
    float* red  = (float*)smem;             // epilogue (As dead by then)

    const int b = blockIdx.x;
    const int t = threadIdx.x;
    const int w = t >> 6;        // 0..15
    const int l = t & 63;

    if (t < 256) sacc[t] = 0.f;
    if (b == 0) {
        if (t == 0) { *T = 0.f; *cnt = 0u; }
        if (t < 256) s[t] = 0.f;
    }
    __syncthreads();

    // ---- P1: rowsum + fp8 convert; wave w owns rows b*32 + w*2 + {0,1}
    #pragma unroll
    for (int h = 0; h < 2; ++h) {
        const int row = b * 32 + w * 2 + h;
        const float4* rp = reinterpret_cast<const float4*>(A + (size_t)row * Nn);
        unsigned int* wp = reinterpret_cast<unsigned int*>(Af8 + (size_t)row * Nn);
        float sum = 0.f;
        #pragma unroll 4
        for (int i = 0; i < 32; ++i) {
            float4 v = rp[i * 64 + l];
            sum += (v.x + v.y) + (v.z + v.w);
            int p = __builtin_amdgcn_cvt_pk_fp8_f32(v.x, v.y, 0, false);
            p     = __builtin_amdgcn_cvt_pk_fp8_f32(v.z, v.w, p, true);
            wp[i * 64 + l] = (unsigned int)p;
        }
        #pragma unroll
        for (int off = 32; off > 0; off >>= 1) sum += __shfl_down(sum, off, 64);
        if (l == 0) {
            float rs = sum + 1e-10f;
            disL[w * 2 + h] = rsqrtf(rs);
            rdL [w * 2 + h] = sqrtf(rs);
        }
    }

    // ---- P2: Y for own rows (dis is wave-local!), Yr + fp8-T tile + sacc
    #pragma unroll
    for (int h = 0; h < 2; ++h) {
        const int lr  = w * 2 + h;
        const int row = b * 32 + lr;
        float4 v = reinterpret_cast<const float4*>(Z + (size_t)row * Dd)[l];
        float ss = v.x*v.x + v.y*v.y + v.z*v.z + v.w*v.w;
        #pragma unroll
        for (int off = 32; off > 0; off >>= 1) ss += __shfl_down(ss, off, 64);
        ss = __shfl(ss, 0, 64);
        const float dis = disL[lr], rd = rdL[lr];
        const float sc  = dis / fmaxf(sqrtf(ss), 1e-12f);
        const float sc8 = 64.f * sc;
        const float y0 = v.x*sc, y1 = v.y*sc, y2 = v.z*sc, y3 = v.w*sc;
        *reinterpret_cast<f16x4*>(Yr + (size_t)row * Dd + l * 4) =
            f16x4{ (_Float16)y0, (_Float16)y1, (_Float16)y2, (_Float16)y3 };
        int p = __builtin_amdgcn_cvt_pk_fp8_f32(v.x*sc8, v.y*sc8, 0, false);
        p     = __builtin_amdgcn_cvt_pk_fp8_f32(v.z*sc8, v.w*sc8, p, true);
        tile[l*4+0][lr] = (unsigned char)(p);
        tile[l*4+1][lr] = (unsigned char)(p >> 8);
        tile[l*4+2][lr] = (unsigned char)(p >> 16);
        tile[l*4+3][lr] = (unsigned char)(p >> 24);
        atomicAdd(&sacc[l*4+0], rd * y0);
        atomicAdd(&sacc[l*4+1], rd * y1);
        atomicAdd(&sacc[l*4+2], rd * y2);
        atomicAdd(&sacc[l*4+3], rd * y3);
    }
    __syncthreads();
    {   // tile readout: thread t -> n = t>>2, 8 bytes of Ytf8[n][b*32+..]
        const int n = t >> 2, sg = (t & 3) * 8;
        *reinterpret_cast<long*>(Ytf8 + (size_t)n * Nn + b * 32 + sg) =
            *reinterpret_cast<const long*>(&tile[n][sg]);
    }

    __threadfence();
    cg::this_grid().sync();
    WAITV(0);
    if (t < 256) atomicAdd(&s[t], sacc[t]);   // flush block-local colsum
    WAITV(0);
    __syncthreads();

    // ---- P3: GEMM (round-10 k_main verbatim) ------------------------------
    char* As8 = smem;            // 64 KB (4 x 16 KB)
    char* Ys8 = smem + 65536;    // 64 KB
    const int ib = b & 31, jb = b >> 5;
    const int I0 = ib * BM, K0 = jb * KC;
    const int wm = w >> 1, wn = w & 1;
    const int ln = l & 31, lkh = l >> 5;

    f32x16 acc[4];
    #pragma unroll
    for (int q = 0; q < 4; ++q) acc[q] = (f32x16)(0.f);

    #define STAGE(SC, B)                                                       \
    {   const int kc = K0 + (SC) * SK;                                         \
        const int rr = w * 16 + (l >> 2);                                      \
        const int sg = ((l & 3) ^ ((rr >> 1) & 3)) * 16;                       \
        __builtin_amdgcn_global_load_lds(                                      \
            (const AS1 unsigned int*)(Af8 + (size_t)(I0 + rr) * Nn + kc + sg), \
            (AS3 unsigned int*)(As8 + (B) * ABYTES + w * 1024), 16, 0, 0);     \
        __builtin_amdgcn_global_load_lds(                                      \
            (const AS1 unsigned int*)(Ytf8 + (size_t)rr * Nn + kc + sg),       \
            (AS3 unsigned int*)(Ys8 + (B) * YBYTES + w * 1024), 16, 0, 0);     \
    }

    STAGE(0, 0); STAGE(1, 1); STAGE(2, 2);

    for (int sc = 0; sc < NSC; ++sc) {
        const int ah = NSC - 1 - sc;
        if (ah >= 2) WAITV(4); else if (ah == 1) WAITV(2); else WAITV(0);
        __builtin_amdgcn_s_barrier();
        if (sc + 3 < NSC) STAGE(sc + 3, (sc + 3) & 3);

        const int cb = sc & 3;
        const long* Al = reinterpret_cast<const long*>(As8 + cb * ABYTES);
        const long* Yl = reinterpret_cast<const long*>(Ys8 + cb * YBYTES);
        const int r  = wm * 32 + ln;
        const int xA = ((r >> 1) & 3) << 1;
        long af[4];
        #pragma unroll
        for (int ks = 0; ks < 4; ++ks) af[ks] = Al[r * 8 + ((ks * 2 + lkh) ^ xA)];
        #pragma unroll
        for (int tn = 0; tn < 4; ++tn) {
            const int n  = wn * 128 + tn * 32 + ln;
            const int xN = ((n >> 1) & 3) << 1;
            #pragma unroll
            for (int ks = 0; ks < 4; ++ks) {
                const long bf = Yl[n * 8 + ((ks * 2 + lkh) ^ xN)];
                acc[tn] = __builtin_amdgcn_mfma_f32_32x32x16_fp8_fp8(af[ks], bf, acc[tn], 0, 0, 0);
            }
        }
    }
    #undef STAGE

    float part = 0.f;
    #pragma unroll
    for (int tn = 0; tn < 4; ++tn) {
        const int n = wn * 128 + tn * 32 + ln;
        #pragma unroll
        for (int rr = 0; rr < 16; ++rr) {
            const int i = I0 + wm * 32 + (rr & 3) + 8 * (rr >> 2) + 4 * lkh;
            part += acc[tn][rr] * (float)Yr[(size_t)i * Dd + n];
        }
    }
    #pragma unroll
    for (int off = 32; off > 0; off >>= 1) part += __shfl_down(part, off, 64);
    if (l == 0) red[w] = part;
    __syncthreads();
    if (t == 0) {
        float tt = 0.f;
        #pragma unroll
        for (int i = 0; i < 16; ++i) tt += red[i];
        atomicAdd(T, tt * 0.015625f);   // 1/64
    }

    // ---- P4: last block finalizes
    __threadfence();
    if (t == 0) islast = (atomicAdd(cnt, 1u) == 255u) ? 1 : 0;
    __syncthreads();
    if (islast) {
        float p = 0.f;
        if (t < 256) { float sv = atomicAdd(&s[t], 0.f); p = sv * sv; }
        #pragma unroll
        for (int off = 32; off > 0; off >>= 1) p += __shfl_down(p, off, 64);
        __syncthreads();              // red region reuse
        if (l == 0) red[w] = p;
        __syncthreads();
        if (t == 0) {
            float ss = 0.f;
            #pragma unroll
            for (int i = 0; i < 16; ++i) ss += red[i];
            const float Tv = atomicAdd(T, 0.f);
            out[0] = -Tv;
            out[1] = ss - Tv;
        }
    }
}

// ===========================================================================
// FALLBACK: round-10 five-kernel path (used only if cooperative launch fails)
// ===========================================================================
__global__ __launch_bounds__(256) void k_rowcvt(const float* __restrict__ A,
                                                unsigned char* __restrict__ Af8,
                                                float* __restrict__ dis,
                                                float* __restrict__ rd,
                                                float* __restrict__ s,
                                                float* __restrict__ T) {
    if (blockIdx.x == 0) {
        if (threadIdx.x == 0) *T = 0.f;
        s[threadIdx.x] = 0.f;
    }
    const int row  = blockIdx.x * 4 + (threadIdx.x >> 6);
    const int lane = threadIdx.x & 63;
    const float4*  rp = reinterpret_cast<const float4*>(A + (size_t)row * Nn);
    unsigned int*  wp = reinterpret_cast<unsigned int*>(Af8 + (size_t)row * Nn);
    float sum = 0.f;
    #pragma unroll
    for (int i = 0; i < Nn / 256; ++i) {
        float4 v = rp[i * 64 + lane];
        sum += (v.x + v.y) + (v.z + v.w);
        int p = __builtin_amdgcn_cvt_pk_fp8_f32(v.x, v.y, 0, false);
        p     = __builtin_amdgcn_cvt_pk_fp8_f32(v.z, v.w, p, true);
        wp[i * 64 + lane] = (unsigned int)p;
    }
    #pragma unroll
    for (int off = 32; off > 0; off >>= 1) sum += __shfl_down(sum, off, 64);
    if (lane == 0) {
        float rs = sum + 1e-10f;
        dis[row] = rsqrtf(rs);
        rd[row]  = sqrtf(rs);
    }
}

__global__ __launch_bounds__(256) void k_makeYt(const float* __restrict__ Z,
                                               const float* __restrict__ dis,
                                               unsigned char* __restrict__ Ytf8,
                                               _Float16* __restrict__ Yr) {
    __shared__ float nrm[64][4];
    __shared__ unsigned char tile[Dd][80];
    const int t = threadIdx.x;
    const int r = t >> 2, q = t & 3;
    const int row = blockIdx.x * 64 + r;
    const float4* zp = reinterpret_cast<const float4*>(Z + (size_t)row * Dd + q * 64);
    float4 v[16];
    float ss = 0.f;
    #pragma unroll
    for (int i = 0; i < 16; ++i) {
        v[i] = zp[i];
        ss += v[i].x*v[i].x + v[i].y*v[i].y + v[i].z*v[i].z + v[i].w*v[i].w;
    }
    nrm[r][q] = ss;
    __syncthreads();
    const float tot  = nrm[r][0] + nrm[r][1] + nrm[r][2] + nrm[r][3];
    const float sc   = dis[row] / fmaxf(sqrtf(tot), 1e-12f);
    const float sc8  = 64.f * sc;
    #pragma unroll
    for (int i = 0; i < 16; ++i) {
        const int c0 = q * 64 + i * 4;
        f16x4 y = { (_Float16)(v[i].x * sc), (_Float16)(v[i].y * sc),
                    (_Float16)(v[i].z * sc), (_Float16)(v[i].w * sc) };
        *reinterpret_cast<f16x4*>(Yr + (size_t)row * Dd + c0) = y;
        int p = __builtin_amdgcn_cvt_pk_fp8_f32(v[i].x * sc8, v[i].y * sc8, 0, false);
        p     = __builtin_amdgcn_cvt_pk_fp8_f32(v[i].z * sc8, v[i].w * sc8, p, true);
        tile[c0+0][r] = (unsigned char)(p);
        tile[c0+1][r] = (unsigned char)(p >> 8);
        tile[c0+2][r] = (unsigned char)(p >> 16);
        tile[c0+3][r] = (unsigned char)(p >> 24);
    }
    __syncthreads();
    int4*       dst = reinterpret_cast<int4*>(Ytf8 + (size_t)t * Nn + blockIdx.x * 64);
    const int4* src = reinterpret_cast<const int4*>(&tile[t][0]);
    #pragma unroll
    for (int i = 0; i < 4; ++i) dst[i] = src[i];
}

__global__ __launch_bounds__(256) void k_colsum(const _Float16* __restrict__ Yr,
                                                const float* __restrict__ rd,
                                                float* __restrict__ s) {
    const int c  = threadIdx.x;
    const int r0 = blockIdx.x * 256;
    float acc = 0.f;
    const _Float16* yp = Yr + (size_t)r0 * Dd + c;
    #pragma unroll 8
    for (int r = 0; r < 256; ++r) acc += (float)yp[(size_t)r * Dd] * rd[r0 + r];
    atomicAdd(&s[c], acc);
}

__global__ __launch_bounds__(1024, 4) void k_main(const unsigned char* __restrict__ Af8,
                                                  const unsigned char* __restrict__ Ytf8,
                                                  const _Float16* __restrict__ Yr,
                                                  float* __restrict__ T) {
    __shared__ long As[NB * ABYTES / 8];
    __shared__ long Ys[NB * YBYTES / 8];
    char* As8 = (char*)As;
    char* Ys8 = (char*)Ys;

    const int ib = blockIdx.x & (Nn / BM - 1);
    const int jb = blockIdx.x >> 5;
    const int I0 = ib * BM;
    const int K0 = jb * KC;
    const int t   = threadIdx.x;
    const int w   = t >> 6;
    const int wm  = w >> 1;
    const int wn  = w & 1;
    const int l   = t & 63;
    const int ln  = l & 31;
    const int lkh = l >> 5;

    f32x16 acc[4];
    #pragma unroll
    for (int q = 0; q < 4; ++q) acc[q] = (f32x16)(0.f);

    #define STAGEF(SC, B)                                                      \
    {   const int kc = K0 + (SC) * SK;                                         \
        const int rr = w * 16 + (l >> 2);                                      \
        const int sg = ((l & 3) ^ ((rr >> 1) & 3)) * 16;                       \
        __builtin_amdgcn_global_load_lds(                                      \
            (const AS1 unsigned int*)(Af8 + (size_t)(I0 + rr) * Nn + kc + sg), \
            (AS3 unsigned int*)(As8 + (B) * ABYTES + w * 1024), 16, 0, 0);     \
        __builtin_amdgcn_global_load_lds(                                      \
            (const AS1 unsigned int*)(Ytf8 + (size_t)rr * Nn + kc + sg),       \
            (AS3 unsigned int*)(Ys8 + (B) * YBYTES + w * 1024), 16, 0, 0);     \
    }

    STAGEF(0, 0); STAGEF(1, 1); STAGEF(2, 2);

    for (int sc = 0; sc < NSC; ++sc) {
        const int ah = NSC - 1 - sc;
        if (ah >= 2) WAITV(4); else if (ah == 1) WAITV(2); else WAITV(0);
        __builtin_amdgcn_s_barrier();
        if (sc + 3 < NSC) STAGEF(sc + 3, (sc + 3) & 3);

        const int cb = sc & 3;
        const long* Al = reinterpret_cast<const long*>(As8 + cb * ABYTES);
        const long* Yl = reinterpret_cast<const long*>(Ys8 + cb * YBYTES);
        const int r  = wm * 32 + ln;
        const int xA = ((r >> 1) & 3) << 1;
        long af[4];
        #pragma unroll
        for (int ks = 0; ks < 4; ++ks) af[ks] = Al[r * 8 + ((ks * 2 + lkh) ^ xA)];
        #pragma unroll
        for (int tn = 0; tn < 4; ++tn) {
            const int n  = wn * 128 + tn * 32 + ln;
            const int xN = ((n >> 1) & 3) << 1;
            #pragma unroll
            for (int ks = 0; ks < 4; ++ks) {
                const long bf = Yl[n * 8 + ((ks * 2 + lkh) ^ xN)];
                acc[tn] = __builtin_amdgcn_mfma_f32_32x32x16_fp8_fp8(af[ks], bf, acc[tn], 0, 0, 0);
            }
        }
    }
    #undef STAGEF

    float part = 0.f;
    #pragma unroll
    for (int tn = 0; tn < 4; ++tn) {
        const int n = wn * 128 + tn * 32 + ln;
        #pragma unroll
        for (int rr = 0; rr < 16; ++rr) {
            const int i = I0 + wm * 32 + (rr & 3) + 8 * (rr >> 2) + 4 * lkh;
            part += acc[tn][rr] * (float)Yr[(size_t)i * Dd + n];
        }
    }
    #pragma unroll
    for (int off = 32; off > 0; off >>= 1) part += __shfl_down(part, off, 64);
    __shared__ float red[16];
    if (l == 0) red[w] = part;
    __syncthreads();
    if (threadIdx.x == 0) {
        float tt = 0.f;
        #pragma unroll
        for (int i = 0; i < 16; ++i) tt += red[i];
        atomicAdd(T, tt * 0.015625f);
    }
}

__global__ __launch_bounds__(256) void k_final(const float* __restrict__ s,
                                               const float* __restrict__ T,
                                               float* __restrict__ out) {
    const int t = threadIdx.x;
    float v = s[t];
    float p = v * v;
    #pragma unroll
    for (int off = 32; off > 0; off >>= 1) p += __shfl_down(p, off, 64);
    __shared__ float red[4];
    if ((t & 63) == 0) red[t >> 6] = p;
    __syncthreads();
    if (t == 0) {
        const float ss = red[0] + red[1] + red[2] + red[3];
        const float Tv = *T;
        out[0] = -Tv;
        out[1] = ss - Tv;
    }
}

// ---------------------------------------------------------------------------
extern "C" void kernel_launch(void* const* d_in, const int* in_sizes, int n_in,
                              void* d_out, int out_size, void* d_ws, size_t ws_size,
                              hipStream_t stream) {
    const float* Z = (const float*)d_in[1];
    const float* A = (const float*)d_in[2];
    float* out = (float*)d_out;

    char* ws = (char*)d_ws;
    float*         dis  = (float*)(ws);                          // fallback only
    float*         rd   = (float*)(ws + 32768);                  // fallback only
    float*         s    = (float*)(ws + 65536);                  // 1 KB
    float*         T    = (float*)(ws + 66560);                  // 4 B
    unsigned int*  cnt  = (unsigned int*)(ws + 66564);           // 4 B
    _Float16*      Yr   = (_Float16*)(ws + 131072);              // 4 MB
    unsigned char* Ytf8 = (unsigned char*)(ws + 131072 + (size_t)Nn * Dd * 2);  // 2 MB
    unsigned char* Af8  = (unsigned char*)(ws + 131072 + (size_t)Nn * Dd * 3);  // 64 MB

    void* args[] = { (void*)&A, (void*)&Z, (void*)&Af8, (void*)&Ytf8,
                     (void*)&Yr, (void*)&s, (void*)&T, (void*)&cnt, (void*)&out };
    hipError_t err = hipLaunchCooperativeKernel((const void*)k_mega,
                                                dim3(256), dim3(1024),
                                                args, 0, stream);
    if (err != hipSuccess) {
        // fallback: validated round-10 five-kernel path
        k_rowcvt<<<Nn / 4, 256, 0, stream>>>(A, Af8, dis, rd, s, T);
        k_makeYt<<<Nn / 64, 256, 0, stream>>>(Z, dis, Ytf8, Yr);
        k_colsum<<<Nn / 256, 256, 0, stream>>>(Yr, rd, s);
        k_main<<<(Nn / BM) * (Nn / KC), 1024, 0, stream>>>(Af8, Ytf8, Yr, T);
        k_final<<<1, 256, 0, stream>>>(s, T, out);
    }
}

// Round 12
// 188.073 us; speedup vs baseline: 1.7368x; 1.7368x over previous
//
#include <hip/hip_runtime.h>
#include <hip/hip_fp16.h>

typedef _Float16 f16x4  __attribute__((ext_vector_type(4)));
typedef float    f32x16 __attribute__((ext_vector_type(16)));

constexpr int Nn = 8192;
constexpr int Dd = 256;

constexpr int BM  = 128;        // I-rows per GEMM block (512 thr, 2 blocks/CU)
constexpr int KC  = 1024;       // K range per block
constexpr int SK  = 64;         // staged K subchunk (64 B/row)
constexpr int NSC = KC / SK;    // 16 subchunks
constexpr int ABYTES = BM * SK; //  8 KB per A buffer (fp8)
constexpr int YBYTES = Dd * SK; // 16 KB per Yt buffer (fp8)

#define AS1 __attribute__((address_space(1)))
#define AS3 __attribute__((address_space(3)))
#define WAITV(N) asm volatile("s_waitcnt vmcnt(" #N ")" ::: "memory")

// ---------------------------------------------------------------------------
// K1: rowsum of A -> dis = rsqrt(sum+1e-10), rd = sqrt(sum+1e-10);
//     writes Af8 = e4m3(A) (64 MB). Zeroes s/T/cnt. At BW floor (6.27 TB/s).
__global__ __launch_bounds__(256) void k_rowcvt(const float* __restrict__ A,
                                                unsigned char* __restrict__ Af8,
                                                float* __restrict__ dis,
                                                float* __restrict__ rd,
                                                float* __restrict__ s,
                                                float* __restrict__ T,
                                                unsigned int* __restrict__ cnt) {
    if (blockIdx.x == 0) {
        if (threadIdx.x == 0) { *T = 0.f; *cnt = 0u; }
        s[threadIdx.x] = 0.f;
    }
    const int row  = blockIdx.x * 4 + (threadIdx.x >> 6);
    const int lane = threadIdx.x & 63;
    const float4*  rp = reinterpret_cast<const float4*>(A + (size_t)row * Nn);
    unsigned int*  wp = reinterpret_cast<unsigned int*>(Af8 + (size_t)row * Nn);
    float sum = 0.f;
    #pragma unroll
    for (int i = 0; i < Nn / 256; ++i) {
        float4 v = rp[i * 64 + lane];
        sum += (v.x + v.y) + (v.z + v.w);
        int p = __builtin_amdgcn_cvt_pk_fp8_f32(v.x, v.y, 0, false);
        p     = __builtin_amdgcn_cvt_pk_fp8_f32(v.z, v.w, p, true);
        wp[i * 64 + lane] = (unsigned int)p;
    }
    #pragma unroll
    for (int off = 32; off > 0; off >>= 1) sum += __shfl_down(sum, off, 64);
    if (lane == 0) {
        float rs = sum + 1e-10f;
        dis[row] = rsqrtf(rs);
        rd[row]  = sqrtf(rs);
    }
}

// ---------------------------------------------------------------------------
// K2: Y = dis * Z/||Z||. Writes Ytf8[256 n][8192 i] = e4m3(64*Y) and
//     Yr[8192][256] f16 (true Y, for epilogue + colsum).
__global__ __launch_bounds__(256) void k_makeYt(const float* __restrict__ Z,
                                               const float* __restrict__ dis,
                                               unsigned char* __restrict__ Ytf8,
                                               _Float16* __restrict__ Yr) {
    __shared__ float nrm[64][4];
    __shared__ unsigned char tile[Dd][80];
    const int t = threadIdx.x;
    const int r = t >> 2, q = t & 3;
    const int row = blockIdx.x * 64 + r;
    const float4* zp = reinterpret_cast<const float4*>(Z + (size_t)row * Dd + q * 64);
    float4 v[16];
    float ss = 0.f;
    #pragma unroll
    for (int i = 0; i < 16; ++i) {
        v[i] = zp[i];
        ss += v[i].x*v[i].x + v[i].y*v[i].y + v[i].z*v[i].z + v[i].w*v[i].w;
    }
    nrm[r][q] = ss;
    __syncthreads();
    const float tot  = nrm[r][0] + nrm[r][1] + nrm[r][2] + nrm[r][3];
    const float sc   = dis[row] / fmaxf(sqrtf(tot), 1e-12f);
    const float sc8  = 64.f * sc;
    #pragma unroll
    for (int i = 0; i < 16; ++i) {
        const int c0 = q * 64 + i * 4;
        f16x4 y = { (_Float16)(v[i].x * sc), (_Float16)(v[i].y * sc),
                    (_Float16)(v[i].z * sc), (_Float16)(v[i].w * sc) };
        *reinterpret_cast<f16x4*>(Yr + (size_t)row * Dd + c0) = y;
        int p = __builtin_amdgcn_cvt_pk_fp8_f32(v[i].x * sc8, v[i].y * sc8, 0, false);
        p     = __builtin_amdgcn_cvt_pk_fp8_f32(v[i].z * sc8, v[i].w * sc8, p, true);
        tile[c0+0][r] = (unsigned char)(p);
        tile[c0+1][r] = (unsigned char)(p >> 8);
        tile[c0+2][r] = (unsigned char)(p >> 16);
        tile[c0+3][r] = (unsigned char)(p >> 24);
    }
    __syncthreads();
    int4*       dst = reinterpret_cast<int4*>(Ytf8 + (size_t)t * Nn + blockIdx.x * 64);
    const int4* src = reinterpret_cast<const int4*>(&tile[t][0]);
    #pragma unroll
    for (int i = 0; i < 4; ++i) dst[i] = src[i];
}

// ---------------------------------------------------------------------------
// K2b: s[k] = sum_j Zn[j][k] = sum_j Yr[j][k] * rd[j]
__global__ __launch_bounds__(256) void k_colsum(const _Float16* __restrict__ Yr,
                                                const float* __restrict__ rd,
                                                float* __restrict__ s) {
    const int c  = threadIdx.x;
    const int r0 = blockIdx.x * 256;
    float acc = 0.f;
    const _Float16* yp = Yr + (size_t)r0 * Dd + c;
    #pragma unroll 8
    for (int r = 0; r < 256; ++r) acc += (float)yp[(size_t)r * Dd] * rd[r0 + r];
    atomicAdd(&s[c], acc);
}

// ---------------------------------------------------------------------------
// K3: T += sum_i Y_i . (A[I,Kchunk] @ Y[Kchunk])   [32x32x16 fp8 MFMA]
// Round-12: 512 thr (8 waves: wm=w>>1 row-stripe, wn=w&1 col-half), BM=128,
// NB=2 double-buffer (48 KB LDS) -> __launch_bounds__(512,4) gives 2
// blocks/CU: independent blocks overlap stage/compute phases (fixes the
// 1-block/CU 2-phase lockstep stall that byte-reduction rounds exposed).
// Per stage: 3 shots/wave (1 A + 2 Yt). r10's validated 16B-XOR swizzle.
// Ticket finalize absorbed (was k_final).
__global__ __launch_bounds__(512, 4) void k_main(const unsigned char* __restrict__ Af8,
                                                 const unsigned char* __restrict__ Ytf8,
                                                 const _Float16* __restrict__ Yr,
                                                 const float* __restrict__ s,
                                                 float* __restrict__ T,
                                                 unsigned int* __restrict__ cnt,
                                                 float* __restrict__ out) {
    __shared__ char As8[2 * ABYTES];   // 16 KB
    __shared__ char Ys8[2 * YBYTES];   // 32 KB
    __shared__ float red[8];
    __shared__ int islast;

    const int ib = blockIdx.x & 63;    // 64 I-tiles (fastest)
    const int jb = blockIdx.x >> 6;    // 8 K-chunks
    const int I0 = ib * BM;
    const int K0 = jb * KC;
    const int t   = threadIdx.x;
    const int w   = t >> 6;            // 0..7
    const int wm  = w >> 1;            // 32-row stripe (0..3)
    const int wn  = w & 1;             // 128-col half
    const int l   = t & 63;
    const int ln  = l & 31;
    const int lkh = l >> 5;

    f32x16 acc[4];
    #pragma unroll
    for (int q = 0; q < 4; ++q) acc[q] = (f32x16)(0.f);

    // Stage subchunk SC into buffer B: wave w covers A rows [w*16,w*16+16)
    // (1 shot) and Yt rows [w*32,w*32+32) (2 shots). Linear LDS dest;
    // source 16B-group pre-swizzled by g ^ ((row>>1)&3).
    #define STAGE(SC, B)                                                       \
    {   const int kc = K0 + (SC) * SK;                                         \
        {   const int rr = w * 16 + (l >> 2);                                  \
            const int sg = ((l & 3) ^ ((rr >> 1) & 3)) * 16;                   \
            __builtin_amdgcn_global_load_lds(                                  \
                (const AS1 unsigned int*)(Af8 + (size_t)(I0 + rr) * Nn + kc + sg), \
                (AS3 unsigned int*)(As8 + (B) * ABYTES + w * 1024), 16, 0, 0); \
        }                                                                      \
        _Pragma("unroll")                                                      \
        for (int q2 = 0; q2 < 2; ++q2) {                                       \
            const int nr = w * 32 + q2 * 16 + (l >> 2);                        \
            const int sg = ((l & 3) ^ ((nr >> 1) & 3)) * 16;                   \
            __builtin_amdgcn_global_load_lds(                                  \
                (const AS1 unsigned int*)(Ytf8 + (size_t)nr * Nn + kc + sg),   \
                (AS3 unsigned int*)(Ys8 + (B) * YBYTES + (w * 32 + q2 * 16) * 64), \
                16, 0, 0);                                                     \
        }                                                                      \
    }

    STAGE(0, 0);

    for (int sc = 0; sc < NSC; ++sc) {
        WAITV(0);                          // drain current buffer's 3 shots
        __builtin_amdgcn_s_barrier();
        if (sc + 1 < NSC) STAGE(sc + 1, (sc + 1) & 1);   // in flight under MFMA

        const int cb = sc & 1;
        const long* Al = reinterpret_cast<const long*>(As8 + cb * ABYTES);
        const long* Yl = reinterpret_cast<const long*>(Ys8 + cb * YBYTES);
        const int r  = wm * 32 + ln;
        const int xA = ((r >> 1) & 3) << 1;
        long af[4];
        #pragma unroll
        for (int ks = 0; ks < 4; ++ks) af[ks] = Al[r * 8 + ((ks * 2 + lkh) ^ xA)];
        #pragma unroll
        for (int tn = 0; tn < 4; ++tn) {
            const int n  = wn * 128 + tn * 32 + ln;
            const int xN = ((n >> 1) & 3) << 1;
            #pragma unroll
            for (int ks = 0; ks < 4; ++ks) {
                const long bf = Yl[n * 8 + ((ks * 2 + lkh) ^ xN)];
                acc[tn] = __builtin_amdgcn_mfma_f32_32x32x16_fp8_fp8(af[ks], bf, acc[tn], 0, 0, 0);
            }
        }
    }
    #undef STAGE

    // epilogue: part = sum over held (64*W)[i][n] * Y[i][n]; 1/64 at the end
    float part = 0.f;
    #pragma unroll
    for (int tn = 0; tn < 4; ++tn) {
        const int n = wn * 128 + tn * 32 + ln;
        #pragma unroll
        for (int rr = 0; rr < 16; ++rr) {
            const int i = I0 + wm * 32 + (rr & 3) + 8 * (rr >> 2) + 4 * lkh;
            part += acc[tn][rr] * (float)Yr[(size_t)i * Dd + n];
        }
    }
    #pragma unroll
    for (int off = 32; off > 0; off >>= 1) part += __shfl_down(part, off, 64);
    if (l == 0) red[w] = part;
    __syncthreads();
    if (t == 0) {
        float tt = 0.f;
        #pragma unroll
        for (int i = 0; i < 8; ++i) tt += red[i];
        atomicAdd(T, tt * 0.015625f);   // 1/64
    }

    // ticket finalize (absorbs k_final)
    __threadfence();
    if (t == 0) islast = (atomicAdd(cnt, 1u) == (unsigned)(gridDim.x - 1)) ? 1 : 0;
    __syncthreads();
    if (islast) {
        float p = 0.f;
        if (t < 256) { const float sv = s[t]; p = sv * sv; }
        #pragma unroll
        for (int off = 32; off > 0; off >>= 1) p += __shfl_down(p, off, 64);
        if (l == 0) red[w] = p;
        __syncthreads();
        if (t == 0) {
            float ss = 0.f;
            #pragma unroll
            for (int i = 0; i < 8; ++i) ss += red[i];
            const float Tv = atomicAdd(T, 0.f);
            out[0] = -Tv;
            out[1] = ss - Tv;
        }
    }
}

// ---------------------------------------------------------------------------
extern "C" void kernel_launch(void* const* d_in, const int* in_sizes, int n_in,
                              void* d_out, int out_size, void* d_ws, size_t ws_size,
                              hipStream_t stream) {
    const float* Z = (const float*)d_in[1];
    const float* A = (const float*)d_in[2];
    float* out = (float*)d_out;

    char* ws = (char*)d_ws;
    float*         dis  = (float*)(ws);                          // 32 KB
    float*         rd   = (float*)(ws + 32768);                  // 32 KB
    float*         s    = (float*)(ws + 65536);                  // 1 KB
    float*         T    = (float*)(ws + 66560);                  // 4 B
    unsigned int*  cnt  = (unsigned int*)(ws + 66564);           // 4 B
    _Float16*      Yr   = (_Float16*)(ws + 131072);              // 4 MB [8192][256]
    unsigned char* Ytf8 = (unsigned char*)(ws + 131072 + (size_t)Nn * Dd * 2);  // 2 MB
    unsigned char* Af8  = (unsigned char*)(ws + 131072 + (size_t)Nn * Dd * 3);  // 64 MB

    k_rowcvt<<<Nn / 4, 256, 0, stream>>>(A, Af8, dis, rd, s, T, cnt);
    k_makeYt<<<Nn / 64, 256, 0, stream>>>(Z, dis, Ytf8, Yr);
    k_colsum<<<Nn / 256, 256, 0, stream>>>(Yr, rd, s);
    k_main<<<(Nn / BM) * (Nn / KC), 512, 0, stream>>>(Af8, Ytf8, Yr, s, T, cnt, out);
}